// Round 8
// baseline (2023.836 us; speedup 1.0000x reference)
//
#include <hip/hip_runtime.h>
#include <hip/hip_bf16.h>
#include <stdint.h>

#define TS 524288u
#define TMASK (TS - 1u)
#define CHUNK 2048            // points per pipeline chunk
#define NPROD 256             // producer blocks (lowest indices -> dispatched first)
#define NBLK  768             // total grid = LDS-limited residency (3 blocks/CU x 256)

typedef __attribute__((ext_vector_type(8))) short bf16x8;
typedef __attribute__((ext_vector_type(4))) short short4v;
typedef __attribute__((ext_vector_type(4))) float f32x4;

__device__ __forceinline__ short f2bf(float f) {
    union { float f; uint32_t u; } v; v.f = f;
    const uint32_t r = (v.u + 0x7fffu + ((v.u >> 16) & 1u)) >> 16;  // RNE
    return (short)r;
}
__device__ __forceinline__ float bflo(uint32_t u) { return __uint_as_float(u << 16); }
__device__ __forceinline__ float bfhi(uint32_t u) { return __uint_as_float(u & 0xffff0000u); }

__constant__ float c_NLf[16] = {16.f,22.f,30.f,42.f,58.f,80.f,111.f,153.f,
                                212.f,293.f,406.f,561.f,775.f,1071.f,1481.f,2046.f};

// K0a: f32 tables -> packed bf16 dwords (32 MB; 2 MB/level).
__global__ __launch_bounds__(256)
void cvt_tables(const float2* __restrict__ src, uint32_t* __restrict__ dst, int npairs)
{
    const int i = blockIdx.x * 256 + threadIdx.x;
    if (i >= npairs) return;
    const float2 v = src[i];
    dst[i] = (uint32_t)(uint16_t)f2bf(v.x) | ((uint32_t)(uint16_t)f2bf(v.y) << 16);
}

// K0b: zero the chunk-ready flags (ws is re-poisoned to 0xAA every launch).
__global__ __launch_bounds__(256)
void zero_flags(uint32_t* __restrict__ flags, int nflags)
{
    for (int i = threadIdx.x; i < nflags; i += 256) flags[i] = 0u;
}

// encode one point at one level -> packed bf16 feature dword
__device__ __forceinline__ uint32_t encode_pl(float sx, float sy, float sz,
                                              int l, const uint32_t* __restrict__ tb16)
{
    const float nf = c_NLf[l];
    const float xn0 = sx * nf, xn1 = sy * nf, xn2 = sz * nf;
    const float fl0 = floorf(xn0), fl1 = floorf(xn1), fl2 = floorf(xn2);
    const float w0 = xn0 - fl0, w1 = xn1 - fl1, w2 = xn2 - fl2;
    const uint32_t f0 = (uint32_t)fl0, f1 = (uint32_t)fl1, f2 = (uint32_t)fl2;
    const uint32_t c0 = (uint32_t)ceilf(xn0);
    const uint32_t c1 = (uint32_t)ceilf(xn1);
    const uint32_t c2 = (uint32_t)ceilf(xn2);
    const uint32_t hyf = f1 * 2654435761u, hyc = c1 * 2654435761u;
    const uint32_t hzf = f2 * 805459861u,  hzc = c2 * 805459861u;
    const uint32_t* tb = tb16 + (size_t)l * TS;
    const uint32_t e0 = tb[(f0 ^ hyf ^ hzf) & TMASK];
    const uint32_t e1 = tb[(c0 ^ hyf ^ hzf) & TMASK];
    const uint32_t e2 = tb[(f0 ^ hyc ^ hzf) & TMASK];
    const uint32_t e3 = tb[(c0 ^ hyc ^ hzf) & TMASK];
    const uint32_t e4 = tb[(f0 ^ hyf ^ hzc) & TMASK];
    const uint32_t e5 = tb[(c0 ^ hyf ^ hzc) & TMASK];
    const uint32_t e6 = tb[(f0 ^ hyc ^ hzc) & TMASK];
    const uint32_t e7 = tb[(c0 ^ hyc ^ hzc) & TMASK];

    const float u0 = 1.0f - w0, u1 = 1.0f - w1, u2 = 1.0f - w2;
    float a0, a1;
    a0 = u0*u1*u2 * bflo(e0);              a1 = u0*u1*u2 * bfhi(e0);
    a0 = fmaf(w0*u1*u2, bflo(e1), a0);     a1 = fmaf(w0*u1*u2, bfhi(e1), a1);
    a0 = fmaf(u0*w1*u2, bflo(e2), a0);     a1 = fmaf(u0*w1*u2, bfhi(e2), a1);
    a0 = fmaf(w0*w1*u2, bflo(e3), a0);     a1 = fmaf(w0*w1*u2, bfhi(e3), a1);
    a0 = fmaf(u0*u1*w2, bflo(e4), a0);     a1 = fmaf(u0*u1*w2, bfhi(e4), a1);
    a0 = fmaf(w0*u1*w2, bflo(e5), a0);     a1 = fmaf(w0*u1*w2, bfhi(e5), a1);
    a0 = fmaf(u0*w1*w2, bflo(e6), a0);     a1 = fmaf(u0*w1*w2, bfhi(e6), a1);
    a0 = fmaf(w0*w1*w2, bflo(e7), a0);     a1 = fmaf(w0*w1*w2, bfhi(e7), a1);
    return (uint32_t)(uint16_t)f2bf(a0) | ((uint32_t)(uint16_t)f2bf(a1) << 16);
}

// ---------------------------------------------------------------------------
// Pipelined encode + MFMA MLP in ONE kernel (block specialization).
// Blocks [0,NPROD): producers. pair g = b&7 (XCD affinity, 4 MB tables/XCD),
//   sub s = b>>3 covers chunks s, s+32, ... Release-publish done[c] (8 = ready).
// Blocks [NPROD,NBLK): consumers. Prepack weights once; each WAVE owns
//   16-point tiles (per-wave act buffers; no inter-wave barriers), acquire-
//   spins on its tile's chunk flag, then runs the 5-layer MFMA MLP.
// Deadlock-free: producers never wait and have the lowest block indices.
// ---------------------------------------------------------------------------
#define ACT_STRIDE 72

__global__ __launch_bounds__(256)
void ngp_pipe(const float* __restrict__ xg, const float* __restrict__ dg,
              const uint32_t* __restrict__ tb16, uint2* __restrict__ feats_pr,
              uint32_t* __restrict__ done,
              const float* __restrict__ dW1, const float* __restrict__ db1,
              const float* __restrict__ dW2, const float* __restrict__ db2,
              const float* __restrict__ cW1, const float* __restrict__ cb1,
              const float* __restrict__ cW2, const float* __restrict__ cb2,
              const float* __restrict__ cW3, const float* __restrict__ cb3,
              float* __restrict__ out, int n)
{
    __shared__ __align__(16) short w1[2048];
    __shared__ __align__(16) short w2[1024];
    __shared__ __align__(16) short w3[4096];
    __shared__ __align__(16) short w4[4096];
    __shared__ __align__(16) short w5[1024];
    __shared__ float b1[64], b2[16], b3[64], b4[64], b5[16];
    __shared__ __align__(16) short act[4][2][16*ACT_STRIDE];

    const int b   = blockIdx.x;
    const int tid = threadIdx.x;
    const int nchunks = (n + CHUNK - 1) / CHUNK;

    if (b < NPROD) {
        // ======================= PRODUCER =======================
        const int g = b & 7;        // level pair (XCD affinity)
        const int s = b >> 3;       // 0..31
        for (int c = s; c < nchunks; c += NPROD/8) {
            const int base = c * CHUNK;
            const int cnt  = min(CHUNK, n - base);
            for (int i = tid; i < cnt; i += 256) {
                const int p = base + i;
                const float px = xg[3*p+0], py = xg[3*p+1], pz = xg[3*p+2];
                float sx = px / 3.0f, sy = py / 3.0f, sz = pz / 3.0f;
                uint2 res = make_uint2(0u, 0u);
                if ((fabsf(sx) < 0.5f) && (fabsf(sy) < 0.5f) && (fabsf(sz) < 0.5f)) {
                    sx = fminf(fmaxf(sx + 0.5f, 0.0f), 1.0f);
                    sy = fminf(fmaxf(sy + 0.5f, 0.0f), 1.0f);
                    sz = fminf(fmaxf(sz + 0.5f, 0.0f), 1.0f);
                    res.x = encode_pl(sx, sy, sz, 2*g+0, tb16);
                    res.y = encode_pl(sx, sy, sz, 2*g+1, tb16);
                }
                feats_pr[(size_t)g * n + p] = res;
            }
            __syncthreads();   // all block stores for this chunk issued
            if (tid == 0) {
                __hip_atomic_fetch_add(&done[c], 1u, __ATOMIC_RELEASE,
                                       __HIP_MEMORY_SCOPE_AGENT);
            }
        }
        return;
    }

    // ======================= CONSUMER =======================
    for (int idx = tid; idx < 2048; idx += 256) {
        const int jb = idx >> 9, lane = (idx >> 3) & 63, e = idx & 7;
        const int j = jb*16 + (lane & 15), k = ((lane >> 4) << 3) + e;
        w1[idx] = f2bf(dW1[k*64 + j]);
    }
    for (int idx = tid; idx < 1024; idx += 256) {
        const int kb = idx >> 9, lane = (idx >> 3) & 63, e = idx & 7;
        const int j = lane & 15, k = kb*32 + ((lane >> 4) << 3) + e;
        w2[idx] = f2bf(dW2[k*16 + j]);
    }
    for (int idx = tid; idx < 4096; idx += 256) {
        const int jb = idx >> 10, kb = (idx >> 9) & 1, lane = (idx >> 3) & 63, e = idx & 7;
        const int j = jb*16 + (lane & 15), k = kb*32 + ((lane >> 4) << 3) + e;
        w3[idx] = (k < 43) ? f2bf(cW1[k*64 + j]) : (short)0;
        w4[idx] = f2bf(cW2[k*64 + j]);
    }
    for (int idx = tid; idx < 1024; idx += 256) {
        const int kb = idx >> 9, lane = (idx >> 3) & 63, e = idx & 7;
        const int j = lane & 15, k = kb*32 + ((lane >> 4) << 3) + e;
        w5[idx] = (j < 3) ? f2bf(cW3[k*3 + j]) : (short)0;
    }
    if (tid < 64) { b1[tid] = db1[tid]; b3[tid] = cb1[tid]; b4[tid] = cb2[tid]; }
    if (tid < 16) { b2[tid] = db2[tid]; b5[tid] = (tid < 3) ? cb3[tid] : 0.0f; }
    __syncthreads();   // only block barrier; weights read-only afterwards

    const int wv = tid >> 6, lane = tid & 63;
    const int p16 = lane & 15, quad = lane >> 4;
    short* buf0 = &act[wv][0][0];
    short* buf1 = &act[wv][1][0];

    const int nwaves  = (NBLK - NPROD) * 4;
    const int mywave  = (b - NPROD) * 4 + wv;
    const int ntiles  = (n + 15) >> 4;                 // 16-point tiles per wave
    const int tiles_per_chunk = CHUNK / 16;

    for (int t = mywave; t < ntiles; t += nwaves) {
        const int c = t / tiles_per_chunk;             // owning chunk
        // acquire-spin until all 8 pair-planes of chunk c are published
        while (__hip_atomic_load(&done[c], __ATOMIC_ACQUIRE,
                                 __HIP_MEMORY_SCOPE_AGENT) < 8u) {
            __builtin_amdgcn_s_sleep(8);
        }

        const int pp_raw = t*16 + p16;
        const int pp = (pp_raw < n) ? pp_raw : (n - 1);
        const bool valid = (pp_raw < n);

        const float mx = xg[3*pp+0] / 3.0f, my = xg[3*pp+1] / 3.0f, mz = xg[3*pp+2] / 3.0f;
        const bool inside = (fabsf(mx) < 0.5f) && (fabsf(my) < 0.5f) && (fabsf(mz) < 0.5f);

        // B-frag: k=quad*8+e -> level 4*quad+(e>>1) -> pairs 2q, 2q+1
        union { uint2 u[2]; bf16x8 v; } bu;
        bu.u[0] = feats_pr[(size_t)(2*quad+0)*n + pp];
        bu.u[1] = feats_pr[(size_t)(2*quad+1)*n + pp];
        const bf16x8 bA = bu.v;

        // ---- L1: feats[32] -> hid[64], relu ----
        #pragma unroll
        for (int jb = 0; jb < 4; ++jb) {
            const int j0 = jb*16 + quad*4;
            f32x4 acc = { b1[j0], b1[j0+1], b1[j0+2], b1[j0+3] };
            const bf16x8 aF = *reinterpret_cast<const bf16x8*>(&w1[(jb*64 + lane)*8]);
            acc = __builtin_amdgcn_mfma_f32_16x16x32_bf16(aF, bA, acc, 0, 0, 0);
            short4v s;
            s[0] = f2bf(fmaxf(acc[0], 0.f)); s[1] = f2bf(fmaxf(acc[1], 0.f));
            s[2] = f2bf(fmaxf(acc[2], 0.f)); s[3] = f2bf(fmaxf(acc[3], 0.f));
            *reinterpret_cast<short4v*>(&buf0[p16*ACT_STRIDE + j0]) = s;
        }

        // ---- L2: hid[64] -> h16[16] ----
        f32x4 acc2 = { b2[quad*4], b2[quad*4+1], b2[quad*4+2], b2[quad*4+3] };
        #pragma unroll
        for (int kb = 0; kb < 2; ++kb) {
            const bf16x8 bF = *reinterpret_cast<const bf16x8*>(&buf0[p16*ACT_STRIDE + kb*32 + quad*8]);
            const bf16x8 aF = *reinterpret_cast<const bf16x8*>(&w2[(kb*64 + lane)*8]);
            acc2 = __builtin_amdgcn_mfma_f32_16x16x32_bf16(aF, bF, acc2, 0, 0, 0);
        }
        if (quad == 0 && valid)
            out[(size_t)3*n + pp] = inside ? __expf(acc2[0]) : 0.0f;
        {
            short4v s;
            s[0] = f2bf(acc2[0]); s[1] = f2bf(acc2[1]);
            s[2] = f2bf(acc2[2]); s[3] = f2bf(acc2[3]);
            *reinterpret_cast<short4v*>(&buf1[p16*ACT_STRIDE + quad*4]) = s;
        }
        {   // pos-enc -> buf1[p][16..42], zeros [43..63]
            const float d0 = dg[3*pp+0], d1 = dg[3*pp+1], d2 = dg[3*pp+2];
            for (int idx = 16 + quad; idx < 64; idx += 4) {
                float val = 0.0f;
                if (idx < 19) {
                    val = (idx == 16) ? d0 : ((idx == 17) ? d1 : d2);
                } else if (idx < 43) {
                    const int g = idx - 19, f = g / 6, rem = g - 6*f;
                    const int c2i = (rem < 3) ? rem : rem - 3;
                    const float arg = ((c2i == 0) ? d0 : ((c2i == 1) ? d1 : d2)) * (float)(1 << f);
                    val = (rem < 3) ? __sinf(arg) : __cosf(arg);
                }
                buf1[p16*ACT_STRIDE + idx] = f2bf(val);
            }
        }

        // ---- L3 ----
        #pragma unroll
        for (int jb = 0; jb < 4; ++jb) {
            const int j0 = jb*16 + quad*4;
            f32x4 acc = { b3[j0], b3[j0+1], b3[j0+2], b3[j0+3] };
            #pragma unroll
            for (int kb = 0; kb < 2; ++kb) {
                const bf16x8 bF = *reinterpret_cast<const bf16x8*>(&buf1[p16*ACT_STRIDE + kb*32 + quad*8]);
                const bf16x8 aF = *reinterpret_cast<const bf16x8*>(&w3[((jb*2 + kb)*64 + lane)*8]);
                acc = __builtin_amdgcn_mfma_f32_16x16x32_bf16(aF, bF, acc, 0, 0, 0);
            }
            short4v s;
            s[0] = f2bf(fmaxf(acc[0], 0.f)); s[1] = f2bf(fmaxf(acc[1], 0.f));
            s[2] = f2bf(fmaxf(acc[2], 0.f)); s[3] = f2bf(fmaxf(acc[3], 0.f));
            *reinterpret_cast<short4v*>(&buf0[p16*ACT_STRIDE + j0]) = s;
        }

        // ---- L4 ----
        #pragma unroll
        for (int jb = 0; jb < 4; ++jb) {
            const int j0 = jb*16 + quad*4;
            f32x4 acc = { b4[j0], b4[j0+1], b4[j0+2], b4[j0+3] };
            #pragma unroll
            for (int kb = 0; kb < 2; ++kb) {
                const bf16x8 bF = *reinterpret_cast<const bf16x8*>(&buf0[p16*ACT_STRIDE + kb*32 + quad*8]);
                const bf16x8 aF = *reinterpret_cast<const bf16x8*>(&w4[((jb*2 + kb)*64 + lane)*8]);
                acc = __builtin_amdgcn_mfma_f32_16x16x32_bf16(aF, bF, acc, 0, 0, 0);
            }
            short4v s;
            s[0] = f2bf(fmaxf(acc[0], 0.f)); s[1] = f2bf(fmaxf(acc[1], 0.f));
            s[2] = f2bf(fmaxf(acc[2], 0.f)); s[3] = f2bf(fmaxf(acc[3], 0.f));
            *reinterpret_cast<short4v*>(&buf1[p16*ACT_STRIDE + j0]) = s;
        }

        // ---- L5 + sigmoid + store ----
        f32x4 acc5 = { b5[quad*4], b5[quad*4+1], b5[quad*4+2], b5[quad*4+3] };
        #pragma unroll
        for (int kb = 0; kb < 2; ++kb) {
            const bf16x8 bF = *reinterpret_cast<const bf16x8*>(&buf1[p16*ACT_STRIDE + kb*32 + quad*8]);
            const bf16x8 aF = *reinterpret_cast<const bf16x8*>(&w5[(kb*64 + lane)*8]);
            acc5 = __builtin_amdgcn_mfma_f32_16x16x32_bf16(aF, bF, acc5, 0, 0, 0);
        }
        if (quad == 0 && valid) {
            #pragma unroll
            for (int r = 0; r < 3; ++r) {
                const float s = 1.0f / (1.0f + __expf(-acc5[r]));
                out[3*pp + r] = inside ? s : 0.0f;
            }
        }
    }
}

extern "C" void kernel_launch(void* const* d_in, const int* in_sizes, int n_in,
                              void* d_out, int out_size, void* d_ws, size_t ws_size,
                              hipStream_t stream)
{
    const float* x   = (const float*)d_in[0];
    const float* d   = (const float*)d_in[1];
    const float* tb  = (const float*)d_in[2];
    const float* dW1 = (const float*)d_in[3];
    const float* db1 = (const float*)d_in[4];
    const float* dW2 = (const float*)d_in[5];
    const float* db2 = (const float*)d_in[6];
    const float* cW1 = (const float*)d_in[7];
    const float* cb1 = (const float*)d_in[8];
    const float* cW2 = (const float*)d_in[9];
    const float* cb2 = (const float*)d_in[10];
    const float* cW3 = (const float*)d_in[11];
    const float* cb3 = (const float*)d_in[12];
    float* out = (float*)d_out;

    const int n = in_sizes[0] / 3;                             // N_PTS = 1M
    const int nchunks = (n + CHUNK - 1) / CHUNK;
    const size_t feats_bytes = (size_t)n * 8 * sizeof(uint2);  // 64 MB
    const size_t tb16_bytes  = (size_t)16 * TS * 4;            // 32 MB
    const size_t flag_bytes  = ((size_t)nchunks * 4 + 255) & ~(size_t)255;

    uint2*    feats_pr = (uint2*)d_ws;
    uint32_t* tb16     = (uint32_t*)((char*)d_ws + feats_bytes);
    uint32_t* flags    = (uint32_t*)((char*)d_ws + feats_bytes + tb16_bytes);

    // requires 96 MB + flags of workspace (prior rounds confirmed >= 96 MB)
    {
        const int npairs = 16 * (int)TS;
        dim3 block(256), grid((npairs + 255) / 256);
        hipLaunchKernelGGL(cvt_tables, grid, block, 0, stream,
                           (const float2*)tb, tb16, npairs);
    }
    {
        dim3 block(256), grid(1);
        hipLaunchKernelGGL(zero_flags, grid, block, 0, stream, flags, nchunks);
    }
    {
        dim3 block(256), grid(NBLK);
        hipLaunchKernelGGL(ngp_pipe, grid, block, 0, stream,
                           x, d, tb16, feats_pr, flags,
                           dW1, db1, dW2, db2,
                           cW1, cb1, cW2, cb2, cW3, cb3, out, n);
    }
}